// Round 1
// baseline (1104.825 us; speedup 1.0000x reference)
//
#include <hip/hip_runtime.h>
#include <math.h>

#define B 2
#define N 8192
#define M 8192
#define D 64
#define KNN 16
#define NSLICE 4
#define SLICE (N / NSLICE)   // 2048
#define BM (B * M)           // 16384

// ---------------------------------------------------------------------------
// ws layout (all fp32/int32 words):
//   f      : B*N*D        = 1,048,576 floats   (projected features)
//   part_d : BM*NSLICE*16 = 1,048,576 floats   layout [(s*16+r)*BM + gq]
//   part_i : BM*NSLICE*16 = 1,048,576 ints     same layout
//   idx    : BM*16        =   262,144 ints     layout [r*BM + gq]
// total ≈ 13.6 MB
// ---------------------------------------------------------------------------

// Kernel 1: f = feature1 @ Wp + bp.  One wave per row, lane = output channel.
__global__ __launch_bounds__(256) void k_proj(const float* __restrict__ feat,
                                              const float* __restrict__ Wp,
                                              const float* __restrict__ bp,
                                              float* __restrict__ f) {
    int lane = threadIdx.x & 63;
    int row  = blockIdx.x * 4 + (threadIdx.x >> 6);   // 0 .. B*N-1
    float fv  = feat[(size_t)row * 64 + lane];
    float acc = bp[lane];
#pragma unroll 8
    for (int d = 0; d < 64; ++d) {
        float x = __shfl(fv, d, 64);
        acc = fmaf(x, Wp[d * 64 + lane], acc);
    }
    f[(size_t)row * 64 + lane] = acc;
}

// Kernel 2: per (query, slice) top-16 of partial d2 = |x|^2 - 2 q.x
// (q^2 added later; constant per query so ordering is unaffected).
// Lane-per-query; slice of xyz1 staged in LDS as float4(x,y,z,|x|^2).
__global__ __launch_bounds__(256) void k_knn_part(const float* __restrict__ xyz1,
                                                  const float* __restrict__ xyz2,
                                                  float* __restrict__ part_d,
                                                  int* __restrict__ part_i) {
    __shared__ float4 pts[SLICE];   // 32 KB
    int bid = blockIdx.x;
    int mg  = bid & 31;             // 32 m-groups of 256
    int b   = (bid >> 5) & 1;
    int s   = bid >> 6;             // 0..NSLICE-1
    int n0  = s * SLICE;

    for (int t = threadIdx.x; t < SLICE; t += 256) {
        const float* p = xyz1 + ((size_t)b * N + n0 + t) * 3;
        float x = p[0], y = p[1], z = p[2];
        pts[t] = make_float4(x, y, z, fmaf(x, x, fmaf(y, y, z * z)));
    }
    __syncthreads();

    int m = mg * 256 + threadIdx.x;
    const float* q = xyz2 + ((size_t)b * M + m) * 3;
    float qx = q[0], qy = q[1], qz = q[2];
    float ax = -2.f * qx, ay = -2.f * qy, az = -2.f * qz;

    float v[KNN];
    int   id[KNN];
#pragma unroll
    for (int r = 0; r < KNN; ++r) { v[r] = 3.4e38f; id[r] = 0; }

#pragma unroll 2
    for (int j = 0; j < SLICE; ++j) {
        float4 p = pts[j];                       // broadcast ds_read_b128
        float d = fmaf(ax, p.x, p.w);
        d = fmaf(ay, p.y, d);
        d = fmaf(az, p.z, d);
        if (d < v[KNN - 1]) {                    // exec-masked slow path
            float dd = d; int ii = n0 + j;
#pragma unroll
            for (int r = 0; r < KNN; ++r) {
                bool  sm = dd < v[r];
                float tv = v[r]; int ti = id[r];
                v[r]  = sm ? dd : tv;  id[r] = sm ? ii : ti;
                dd    = sm ? tv : dd;  ii    = sm ? ti : ii;
            }
        }
    }

    int gq = b * M + m;
#pragma unroll
    for (int r = 0; r < KNN; ++r) {              // coalesced (query-major)
        part_d[(size_t)(s * KNN + r) * BM + gq] = v[r];
        part_i[(size_t)(s * KNN + r) * BM + gq] = id[r];
    }
}

// Kernel 3: merge the NSLICE sorted 16-lists per query; emit final idx list
// and the weight output (uses full d2 = partial + |q|^2).
__global__ __launch_bounds__(256) void k_knn_merge(const float* __restrict__ xyz2,
                                                   const float* __restrict__ part_d,
                                                   const int* __restrict__ part_i,
                                                   int* __restrict__ idx_out,
                                                   float* __restrict__ w_out) {
    int gq = blockIdx.x * 256 + threadIdx.x;     // 0..BM-1
    float v[KNN];
    int   id[KNN];
#pragma unroll
    for (int r = 0; r < KNN; ++r) { v[r] = 3.4e38f; id[r] = 0; }

    for (int e = 0; e < NSLICE * KNN; ++e) {     // slices in ascending-n order
        float d = part_d[(size_t)e * BM + gq];
        if (d < v[KNN - 1]) {
            int ii = part_i[(size_t)e * BM + gq];
            float dd = d;
#pragma unroll
            for (int r = 0; r < KNN; ++r) {
                bool  sm = dd < v[r];
                float tv = v[r]; int ti = id[r];
                v[r]  = sm ? dd : tv;  id[r] = sm ? ii : ti;
                dd    = sm ? tv : dd;  ii    = sm ? ti : ii;
            }
        }
    }

    const float* q = xyz2 + (size_t)gq * 3;
    float q2 = fmaf(q[0], q[0], fmaf(q[1], q[1], q[2] * q[2]));
    float mind = v[0] + q2;
    w_out[gq] = (mind > 0.03f) ? 10.0f : 1.0f;
#pragma unroll
    for (int r = 0; r < KNN; ++r)
        idx_out[(size_t)r * BM + gq] = id[r];
}

// Kernel 4: gather + MLP + reduce.  One wave per query, lane = channel c.
//   h[k][c] = relu(g_xyz[k] . W1[:,c] + b1[c])       (per-lane)
//   y[k][c] = sum_d h[k][d] * W2[d][c]               (via LDS transpose)
//   out[c]  = sum_k (y[k][c] + b2[c]) * f[idx_k][c] * 0.25
__global__ __launch_bounds__(256) void k_final(const float* __restrict__ xyz1,
                                               const float* __restrict__ xyz2,
                                               const float* __restrict__ f,
                                               const int* __restrict__ idx,
                                               const float* __restrict__ W1,
                                               const float* __restrict__ b1,
                                               const float* __restrict__ W2,
                                               const float* __restrict__ b2,
                                               float* __restrict__ out) {
    __shared__ float w2s[64 * 64];      // 16 KB, [d][c]
    __shared__ float hT[4][64 * 16];    // 16 KB, per-wave [d][k]

    for (int t = threadIdx.x; t < 64 * 16; t += 256)
        ((float4*)w2s)[t] = ((const float4*)W2)[t];

    int wv = threadIdx.x >> 6;
    int c  = threadIdx.x & 63;
    int gq = blockIdx.x * 4 + wv;
    int b  = gq >> 13;                  // gq / M

    const float* q = xyz2 + (size_t)gq * 3;
    float qx = q[0], qy = q[1], qz = q[2];
    float w10 = W1[c], w11 = W1[64 + c], w12 = W1[128 + c];
    float b1c = b1[c], b2c = b2[c];

    int nidx[KNN];
#pragma unroll
    for (int k = 0; k < KNN; ++k)
        nidx[k] = idx[(size_t)k * BM + gq];      // wave-broadcast load

    float h[KNN];
#pragma unroll
    for (int k = 0; k < KNN; ++k) {
        const float* p = xyz1 + ((size_t)b * N + nidx[k]) * 3;
        float gx = p[0] - qx, gy = p[1] - qy, gz = p[2] - qz;
        float t = fmaf(gx, w10, b1c);
        t = fmaf(gy, w11, t);
        t = fmaf(gz, w12, t);
        h[k] = fmaxf(t, 0.f);
    }

    // transpose h into LDS: lane c writes hT[wv][c*16 + k]
#pragma unroll
    for (int k = 0; k < KNN; k += 4)
        *(float4*)&hT[wv][c * 16 + k] = make_float4(h[k], h[k+1], h[k+2], h[k+3]);

    __syncthreads();   // covers W2 staging + hT visibility

    float y[KNN];
#pragma unroll
    for (int k = 0; k < KNN; ++k) y[k] = 0.f;

#pragma unroll 4
    for (int d = 0; d < 64; ++d) {
        float w2dc = w2s[d * 64 + c];                    // stride-1, conflict-free
        const float4* hp = (const float4*)&hT[wv][d * 16];  // broadcast reads
        float hh[16];
        *(float4*)&hh[0]  = hp[0];
        *(float4*)&hh[4]  = hp[1];
        *(float4*)&hh[8]  = hp[2];
        *(float4*)&hh[12] = hp[3];
#pragma unroll
        for (int k = 0; k < KNN; ++k)
            y[k] = fmaf(hh[k], w2dc, y[k]);
    }

    float acc = 0.f;
#pragma unroll
    for (int k = 0; k < KNN; ++k) {
        float gfv = f[((size_t)b * N + nidx[k]) * 64 + c];   // coalesced row
        acc = fmaf(y[k] + b2c, gfv, acc);
    }
    out[(size_t)gq * 64 + c] = acc * 0.25f;   // 1/sqrt(16)
}

extern "C" void kernel_launch(void* const* d_in, const int* in_sizes, int n_in,
                              void* d_out, int out_size, void* d_ws, size_t ws_size,
                              hipStream_t stream) {
    const float* feature1 = (const float*)d_in[0];
    const float* xyz1     = (const float*)d_in[1];
    const float* xyz2     = (const float*)d_in[2];
    const float* Wp       = (const float*)d_in[3];
    const float* bp       = (const float*)d_in[4];
    const float* W1       = (const float*)d_in[5];
    const float* b1       = (const float*)d_in[6];
    const float* W2       = (const float*)d_in[7];
    const float* b2       = (const float*)d_in[8];
    float* out = (float*)d_out;

    float* f      = (float*)d_ws;
    float* part_d = f + (size_t)B * N * D;
    int*   part_i = (int*)(part_d + (size_t)BM * NSLICE * KNN);
    int*   idxf   = (int*)(part_i + (size_t)BM * NSLICE * KNN);
    float* w_out  = out + (size_t)BM * D;

    k_proj<<<B * N / 4, 256, 0, stream>>>(feature1, Wp, bp, f);
    k_knn_part<<<(M / 256) * B * NSLICE, 256, 0, stream>>>(xyz1, xyz2, part_d, part_i);
    k_knn_merge<<<BM / 256, 256, 0, stream>>>(xyz2, part_d, part_i, idxf, w_out);
    k_final<<<BM / 4, 256, 0, stream>>>(xyz1, xyz2, f, idxf, W1, b1, W2, b2, out);
}

// Round 2
// 361.917 us; speedup vs baseline: 3.0527x; 3.0527x over previous
//
#include <hip/hip_runtime.h>
#include <math.h>

#define B 2
#define N 8192
#define M 8192
#define D 64
#define KNN 16
#define NSLICE 16
#define SLICE (N / NSLICE)   // 512
#define BM (B * M)           // 16384
#define CAP 32               // per-lane u16 candidate buffer slots

// ---------------------------------------------------------------------------
// ws layout (16B-aligned first):
//   pts4   : B*N float4      = 256 KB   (x,y,z,|p|^2)
//   f      : B*N*D floats    = 4 MB     (projected features)
//   part_i : NSLICE*KNN*BM   = 16 MB    layout [(s*16+r)*BM + gq]
//   idx    : KNN*BM          = 1 MB     layout [r*BM + gq]
// total ~21.3 MB
// ---------------------------------------------------------------------------

// Sorted-insert of (dd,ii) into the per-lane top-16 (v ascending).
// Strict < keeps the earlier-seen (lower index) on exact float ties, matching
// jax.lax.top_k stability. Only the SET matters downstream, but sorted
// maintenance is duplicate-safe (unlike replace-max) and gives min for free.
#define CHAIN_INSERT(DVAL, IVAL) do {                                   \
    float _dd = (DVAL); int _ii = (IVAL);                               \
    _Pragma("unroll")                                                   \
    for (int _r = 0; _r < KNN; ++_r) {                                  \
        bool  _sm = _dd < v[_r];                                        \
        float _tv = v[_r]; int _ti = id[_r];                            \
        v[_r]  = _sm ? _dd : _tv;  id[_r] = _sm ? _ii : _ti;            \
        _dd    = _sm ? _tv : _dd;  _ii    = _sm ? _ti : _ii;            \
    }                                                                   \
} while (0)

// Kernel 0: pts4 = (x, y, z, |p|^2)
__global__ __launch_bounds__(256) void k_prep(const float* __restrict__ xyz1,
                                              float4* __restrict__ pts4) {
    int i = blockIdx.x * 256 + threadIdx.x;      // < B*N
    const float* p = xyz1 + (size_t)i * 3;
    float x = p[0], y = p[1], z = p[2];
    pts4[i] = make_float4(x, y, z, fmaf(x, x, fmaf(y, y, z * z)));
}

// Kernel 1: f = feature1 @ Wp + bp. Wave per row (row-uniform scalar loads),
// lane = output channel. Wp is 16 KB -> L1-resident.
__global__ __launch_bounds__(256) void k_proj(const float* __restrict__ feat,
                                              const float* __restrict__ Wp,
                                              const float* __restrict__ bp,
                                              float* __restrict__ f) {
    int c   = threadIdx.x & 63;
    int row = blockIdx.x * 4 + (threadIdx.x >> 6);   // 0..B*N-1
    const float* fr = feat + (size_t)row * 64;       // wave-uniform -> s_load
    float acc = bp[c];
#pragma unroll 8
    for (int d = 0; d < 64; ++d)
        acc = fmaf(fr[d], Wp[d * 64 + c], acc);
    f[(size_t)row * 64 + c] = acc;
}

// Kernel 2: per (query, slice) top-16 indices of d2' = |p|^2 - 2 q.p
// (|q|^2 constant per query; ordering unaffected).
// Lane-per-query. Candidates read via wave-uniform index (scalar cache).
// Passers buffered per-lane in LDS (u16 local idx); drained at doubling
// checkpoints so the 80-inst insert chain runs ~100x/wave, not ~1700x.
__global__ __launch_bounds__(256) void k_knn_part(const float4* __restrict__ pts4,
                                                  const float* __restrict__ xyz2,
                                                  int* __restrict__ part_i) {
    __shared__ unsigned short ibuf[256 * CAP];   // 16 KB
    int bid = blockIdx.x;
    int mg  = bid & 31;             // 32 m-groups of 256
    int b   = (bid >> 5) & 1;
    int s   = bid >> 6;             // 0..NSLICE-1
    int n0  = s * SLICE;
    int pbase = b * N + n0;

    int m = mg * 256 + threadIdx.x;
    const float* q = xyz2 + ((size_t)(b * M + m)) * 3;
    float qx = q[0], qy = q[1], qz = q[2];
    float ax = -2.f * qx, ay = -2.f * qy, az = -2.f * qz;

    float v[KNN];
    int   id[KNN];
#pragma unroll
    for (int r = 0; r < KNN; ++r) { v[r] = 3.4e38f; id[r] = 0; }

    // init: first 16 candidates straight into the list
#pragma unroll
    for (int j = 0; j < 16; ++j) {
        float4 p = pts4[pbase + j];              // uniform -> s_load
        float dv = fmaf(ax, p.x, p.w);
        dv = fmaf(ay, p.y, dv);
        dv = fmaf(az, p.z, dv);
        CHAIN_INSERT(dv, j);
    }

    float thr = v[KNN - 1];
    int tb  = threadIdx.x * CAP;
    int cnt = 0;
    int j   = 16;

#pragma unroll 1
    for (int sgi = 0; sgi < 5; ++sgi) {
        int e = 32 << sgi;                       // 32,64,128,256,512
#pragma unroll 4
        for (; j < e; ++j) {
            float4 p = pts4[pbase + j];          // uniform -> s_load
            float dv = fmaf(ax, p.x, p.w);
            dv = fmaf(ay, p.y, dv);
            dv = fmaf(az, p.z, dv);
            if (dv < thr) {
                if (cnt < CAP) {
                    ibuf[tb + cnt] = (unsigned short)j;
                    ++cnt;
                } else {                          // overflow fallback (rare)
                    CHAIN_INSERT(dv, j);
                    thr = v[KNN - 1];
                }
            }
        }
        // drain: each lane chain-inserts its own buffered candidates
        int mx = cnt;
#pragma unroll
        for (int off = 32; off; off >>= 1)
            mx = max(mx, __shfl_xor(mx, off, 64));
        for (int t = 0; t < mx; ++t) {
            if (t < cnt) {
                int jj = ibuf[tb + t];
                float4 p = pts4[pbase + jj];     // per-lane gather (L2)
                float dv = fmaf(ax, p.x, p.w);
                dv = fmaf(ay, p.y, dv);
                dv = fmaf(az, p.z, dv);
                CHAIN_INSERT(dv, jj);
            }
        }
        cnt = 0;
        thr = v[KNN - 1];
    }

    int gq = b * M + m;
#pragma unroll
    for (int r = 0; r < KNN; ++r)                // coalesced (query-major)
        part_i[(size_t)(s * KNN + r) * BM + gq] = n0 + id[r];
}

// Kernel 3: merge NSLICE*16 partial indices per query (set-select 16 smallest;
// d recomputed bit-identically from pts4). Emits final idx + weight.
__global__ __launch_bounds__(256) void k_knn_merge(const float4* __restrict__ pts4,
                                                   const float* __restrict__ xyz2,
                                                   const int* __restrict__ part_i,
                                                   int* __restrict__ idx_out,
                                                   float* __restrict__ w_out) {
    int gq = blockIdx.x * 256 + threadIdx.x;     // 0..BM-1
    int b  = gq >> 13;
    const float* q = xyz2 + (size_t)gq * 3;
    float qx = q[0], qy = q[1], qz = q[2];
    float ax = -2.f * qx, ay = -2.f * qy, az = -2.f * qz;

    float v[KNN];
    int   id[KNN];
#pragma unroll
    for (int r = 0; r < KNN; ++r) { v[r] = 3.4e38f; id[r] = 0; }

#pragma unroll 4
    for (int e = 0; e < NSLICE * KNN; ++e) {     // ascending slice, ties stable
        int ii = part_i[(size_t)e * BM + gq];    // coalesced
        float4 p = pts4[b * N + ii];             // gather (L2)
        float dv = fmaf(ax, p.x, p.w);
        dv = fmaf(ay, p.y, dv);
        dv = fmaf(az, p.z, dv);
        CHAIN_INSERT(dv, ii);
    }

    float q2 = fmaf(qx, qx, fmaf(qy, qy, qz * qz));
    float mind = v[0] + q2;
    w_out[gq] = (mind > 0.03f) ? 10.0f : 1.0f;
#pragma unroll
    for (int r = 0; r < KNN; ++r)
        idx_out[(size_t)r * BM + gq] = id[r];
}

// Kernel 4: gather + MLP + reduce. One wave per query, lane = channel c.
// (k-order of neighbors is irrelevant: einsum sums over k.)
__global__ __launch_bounds__(256) void k_final(const float* __restrict__ xyz1,
                                               const float* __restrict__ xyz2,
                                               const float* __restrict__ f,
                                               const int* __restrict__ idx,
                                               const float* __restrict__ W1,
                                               const float* __restrict__ b1,
                                               const float* __restrict__ W2,
                                               const float* __restrict__ b2,
                                               float* __restrict__ out) {
    __shared__ float w2s[64 * 64];      // 16 KB, [d][c]
    __shared__ float hT[4][64 * 16];    // 16 KB, per-wave [d][k]

    for (int t = threadIdx.x; t < 64 * 16; t += 256)
        ((float4*)w2s)[t] = ((const float4*)W2)[t];

    int wv = threadIdx.x >> 6;
    int c  = threadIdx.x & 63;
    int gq = blockIdx.x * 4 + wv;
    int b  = gq >> 13;

    const float* q = xyz2 + (size_t)gq * 3;
    float qx = q[0], qy = q[1], qz = q[2];
    float w10 = W1[c], w11 = W1[64 + c], w12 = W1[128 + c];
    float b1c = b1[c], b2c = b2[c];

    int nidx[KNN];
#pragma unroll
    for (int k = 0; k < KNN; ++k)
        nidx[k] = idx[(size_t)k * BM + gq];      // wave-broadcast load

    float h[KNN];
#pragma unroll
    for (int k = 0; k < KNN; ++k) {
        const float* p = xyz1 + ((size_t)b * N + nidx[k]) * 3;
        float gx = p[0] - qx, gy = p[1] - qy, gz = p[2] - qz;
        float t = fmaf(gx, w10, b1c);
        t = fmaf(gy, w11, t);
        t = fmaf(gz, w12, t);
        h[k] = fmaxf(t, 0.f);
    }

#pragma unroll
    for (int k = 0; k < KNN; k += 4)
        *(float4*)&hT[wv][c * 16 + k] = make_float4(h[k], h[k+1], h[k+2], h[k+3]);

    __syncthreads();   // covers W2 staging + hT visibility

    float y[KNN];
#pragma unroll
    for (int k = 0; k < KNN; ++k) y[k] = 0.f;

#pragma unroll 4
    for (int d = 0; d < 64; ++d) {
        float w2dc = w2s[d * 64 + c];                       // conflict-free
        const float4* hp = (const float4*)&hT[wv][d * 16];  // broadcast reads
        float hh[16];
        *(float4*)&hh[0]  = hp[0];
        *(float4*)&hh[4]  = hp[1];
        *(float4*)&hh[8]  = hp[2];
        *(float4*)&hh[12] = hp[3];
#pragma unroll
        for (int k = 0; k < KNN; ++k)
            y[k] = fmaf(hh[k], w2dc, y[k]);
    }

    float acc = 0.f;
#pragma unroll
    for (int k = 0; k < KNN; ++k) {
        float gfv = f[((size_t)b * N + nidx[k]) * 64 + c];  // coalesced row
        acc = fmaf(y[k] + b2c, gfv, acc);
    }
    out[(size_t)gq * 64 + c] = acc * 0.25f;   // 1/sqrt(16)
}

extern "C" void kernel_launch(void* const* d_in, const int* in_sizes, int n_in,
                              void* d_out, int out_size, void* d_ws, size_t ws_size,
                              hipStream_t stream) {
    const float* feature1 = (const float*)d_in[0];
    const float* xyz1     = (const float*)d_in[1];
    const float* xyz2     = (const float*)d_in[2];
    const float* Wp       = (const float*)d_in[3];
    const float* bp       = (const float*)d_in[4];
    const float* W1       = (const float*)d_in[5];
    const float* b1       = (const float*)d_in[6];
    const float* W2       = (const float*)d_in[7];
    const float* b2       = (const float*)d_in[8];
    float* out = (float*)d_out;

    float4* pts4  = (float4*)d_ws;                           // 16B-aligned base
    float*  f     = (float*)(pts4 + (size_t)B * N);
    int*    parti = (int*)(f + (size_t)B * N * D);
    int*    idxf  = parti + (size_t)NSLICE * KNN * BM;
    float*  w_out = out + (size_t)BM * D;

    k_prep<<<B * N / 256, 256, 0, stream>>>(xyz1, pts4);
    k_proj<<<B * N / 4, 256, 0, stream>>>(feature1, Wp, bp, f);
    k_knn_part<<<(M / 256) * B * NSLICE, 256, 0, stream>>>(pts4, xyz2, parti);
    k_knn_merge<<<BM / 256, 256, 0, stream>>>(pts4, xyz2, parti, idxf, w_out);
    k_final<<<BM / 4, 256, 0, stream>>>(xyz1, xyz2, f, idxf, W1, b1, W2, b2, out);
}

// Round 3
// 341.371 us; speedup vs baseline: 3.2364x; 1.0602x over previous
//
#include <hip/hip_runtime.h>
#include <math.h>

#define B 2
#define N 8192
#define M 8192
#define D 64
#define KNN 16
#define NSLICE 16
#define SLICE (N / NSLICE)   // 512
#define BM (B * M)           // 16384
#define CAP 32               // per-lane candidate buffer slots

// ---------------------------------------------------------------------------
// ws layout (16B-aligned first):
//   pts4   : B*N float4      = 256 KB   (x,y,z,|p|^2)
//   f      : B*N*D floats    = 4 MB
//   part_d : NSLICE*KNN*BM   = 8 MB    layout [(s*16+r)*BM + gq]
//   part_i : NSLICE*KNN*BM   = 8 MB    same layout
//   idx    : KNN*BM          = 1 MB    layout [r*BM + gq]
// total ~21.3 MB (same as round 2)
// ---------------------------------------------------------------------------

// Sorted-insert of (dd,ii) into per-lane top-16 (v ascending). Strict < keeps
// earlier-inserted (lower index) on exact ties, matching top_k stability.
#define CHAIN_INSERT(DVAL, IVAL) do {                                   \
    float _dd = (DVAL); int _ii = (IVAL);                               \
    _Pragma("unroll")                                                   \
    for (int _r = 0; _r < KNN; ++_r) {                                  \
        bool  _sm = _dd < v[_r];                                        \
        float _tv = v[_r]; int _ti = id[_r];                            \
        v[_r]  = _sm ? _dd : _tv;  id[_r] = _sm ? _ii : _ti;            \
        _dd    = _sm ? _tv : _dd;  _ii    = _sm ? _ti : _ii;            \
    }                                                                   \
} while (0)

// Kernel 0: pts4 = (x, y, z, |p|^2)
__global__ __launch_bounds__(256) void k_prep(const float* __restrict__ xyz1,
                                              float4* __restrict__ pts4) {
    int i = blockIdx.x * 256 + threadIdx.x;      // < B*N
    const float* p = xyz1 + (size_t)i * 3;
    float x = p[0], y = p[1], z = p[2];
    pts4[i] = make_float4(x, y, z, fmaf(x, x, fmaf(y, y, z * z)));
}

// Kernel 1: f = feature1 @ Wp + bp. Wave per row, lane = output channel.
__global__ __launch_bounds__(256) void k_proj(const float* __restrict__ feat,
                                              const float* __restrict__ Wp,
                                              const float* __restrict__ bp,
                                              float* __restrict__ f) {
    int c   = threadIdx.x & 63;
    int row = blockIdx.x * 4 + (threadIdx.x >> 6);   // 0..B*N-1
    const float* fr = feat + (size_t)row * 64;       // wave-uniform -> s_load
    float acc = bp[c];
#pragma unroll 8
    for (int d = 0; d < 64; ++d)
        acc = fmaf(fr[d], Wp[d * 64 + c], acc);
    f[(size_t)row * 64 + c] = acc;
}

// Kernel 2: per (query, slice) top-16 of d2' = |p|^2 - 2 q.p  (|q|^2 added
// later; per-query constant, ordering unaffected). Lane-per-query.
// Slice staged in LDS; scan = broadcast ds_read_b128 + 3 FMA + cmp; passers
// buffered (bank-stride-free u16) and chain-inserted only at doubling
// checkpoints; drain re-reads points from the LDS tile.
__global__ __launch_bounds__(256) void k_knn_part(const float4* __restrict__ pts4,
                                                  const float* __restrict__ xyz2,
                                                  float* __restrict__ part_d,
                                                  int* __restrict__ part_i) {
    __shared__ float4 tile[SLICE];                 // 8 KB
    __shared__ unsigned short ibuf[CAP][256];      // 16 KB, [slot][tid] -> 2/bank
    int bid = blockIdx.x;
    int mg  = bid & 31;             // 32 m-groups of 256
    int b   = (bid >> 5) & 1;
    int s   = bid >> 6;             // 0..NSLICE-1
    int n0  = s * SLICE;

    for (int t = threadIdx.x; t < SLICE; t += 256)
        tile[t] = pts4[b * N + n0 + t];
    __syncthreads();

    int m = mg * 256 + threadIdx.x;
    const float* q = xyz2 + ((size_t)(b * M + m)) * 3;
    float qx = q[0], qy = q[1], qz = q[2];
    float ax = -2.f * qx, ay = -2.f * qy, az = -2.f * qz;

    float v[KNN];
    int   id[KNN];
#pragma unroll
    for (int r = 0; r < KNN; ++r) { v[r] = 3.4e38f; id[r] = 0; }

#pragma unroll
    for (int j = 0; j < 16; ++j) {                 // warm the list
        float4 p = tile[j];
        float dv = fmaf(ax, p.x, p.w);
        dv = fmaf(ay, p.y, dv);
        dv = fmaf(az, p.z, dv);
        CHAIN_INSERT(dv, j);
    }

    float thr = v[KNN - 1];
    int cnt = 0;
    int j   = 16;

#pragma unroll 1
    for (int sgi = 0; sgi < 5; ++sgi) {
        int e = 32 << sgi;                         // 32,64,128,256,512
#pragma unroll 4
        for (; j < e; ++j) {
            float4 p = tile[j];                    // broadcast, conflict-free
            float dv = fmaf(ax, p.x, p.w);
            dv = fmaf(ay, p.y, dv);
            dv = fmaf(az, p.z, dv);
            if (dv < thr) {
                if (cnt < CAP) {
                    ibuf[cnt][threadIdx.x] = (unsigned short)j;
                    ++cnt;
                } else {                           // overflow fallback (rare)
                    CHAIN_INSERT(dv, j);
                    thr = v[KNN - 1];
                }
            }
        }
        int mx = cnt;                              // wave-max buffered count
#pragma unroll
        for (int off = 32; off; off >>= 1)
            mx = max(mx, __shfl_xor(mx, off, 64));
        for (int t = 0; t < mx; ++t) {
            bool act = t < cnt;
            int jj = act ? ibuf[t][threadIdx.x] : 0;
            float4 p = tile[jj];                   // LDS gather (small conflicts)
            float dv = fmaf(ax, p.x, p.w);
            dv = fmaf(ay, p.y, dv);
            dv = fmaf(az, p.z, dv);
            if (act && dv < v[KNN - 1])
                CHAIN_INSERT(dv, jj);
        }
        cnt = 0;
        thr = v[KNN - 1];
    }

    int gq = b * M + m;
#pragma unroll
    for (int r = 0; r < KNN; ++r) {                // coalesced (query-major)
        part_d[(size_t)(s * KNN + r) * BM + gq] = v[r];
        part_i[(size_t)(s * KNN + r) * BM + gq] = n0 + id[r];
    }
}

// Kernel 3: merge NSLICE*16 partials per query. 2-stage: 4 subs x 64 entries
// (coalesced loads) -> LDS -> sub 0 merges 4x16. Emits final idx + weight.
__global__ __launch_bounds__(256) void k_knn_merge(const float* __restrict__ xyz2,
                                                   const float* __restrict__ part_d,
                                                   const int* __restrict__ part_i,
                                                   int* __restrict__ idx_out,
                                                   float* __restrict__ w_out) {
    __shared__ float sd[4][KNN][64];    // 16 KB
    __shared__ int   si[4][KNN][64];    // 16 KB
    int ql  = threadIdx.x & 63;
    int sub = threadIdx.x >> 6;
    int gq  = blockIdx.x * 64 + ql;     // 0..BM-1

    float v[KNN];
    int   id[KNN];
#pragma unroll
    for (int r = 0; r < KNN; ++r) { v[r] = 3.4e38f; id[r] = 0; }

#pragma unroll 4
    for (int e = sub * 64; e < sub * 64 + 64; ++e) {   // ascending slice order
        float dv = part_d[(size_t)e * BM + gq];        // coalesced
        if (dv < v[KNN - 1]) {
            int ii = part_i[(size_t)e * BM + gq];
            CHAIN_INSERT(dv, ii);
        }
    }
#pragma unroll
    for (int r = 0; r < KNN; ++r) { sd[sub][r][ql] = v[r]; si[sub][r][ql] = id[r]; }
    __syncthreads();

    if (sub == 0) {
        for (int e = KNN; e < 4 * KNN; ++e) {          // subs 1..3, slice order
            float dv = sd[e >> 4][e & 15][ql];
            if (dv < v[KNN - 1])
                CHAIN_INSERT(dv, si[e >> 4][e & 15][ql]);
        }
        const float* q = xyz2 + (size_t)gq * 3;
        float q2 = fmaf(q[0], q[0], fmaf(q[1], q[1], q[2] * q[2]));
        w_out[gq] = (v[0] + q2 > 0.03f) ? 10.0f : 1.0f;
#pragma unroll
        for (int r = 0; r < KNN; ++r)
            idx_out[(size_t)r * BM + gq] = id[r];
    }
}

// Kernel 4: gather + MLP + reduce. One wave per query, lane = channel c.
__global__ __launch_bounds__(256) void k_final(const float* __restrict__ xyz1,
                                               const float* __restrict__ xyz2,
                                               const float* __restrict__ f,
                                               const int* __restrict__ idx,
                                               const float* __restrict__ W1,
                                               const float* __restrict__ b1,
                                               const float* __restrict__ W2,
                                               const float* __restrict__ b2,
                                               float* __restrict__ out) {
    __shared__ float w2s[64 * 64];      // 16 KB, [d][c]
    __shared__ float hT[4][64 * 16];    // 16 KB, per-wave [d][k]

    for (int t = threadIdx.x; t < 64 * 16; t += 256)
        ((float4*)w2s)[t] = ((const float4*)W2)[t];

    int wv = threadIdx.x >> 6;
    int c  = threadIdx.x & 63;
    int gq = blockIdx.x * 4 + wv;
    int b  = gq >> 13;

    const float* q = xyz2 + (size_t)gq * 3;
    float qx = q[0], qy = q[1], qz = q[2];
    float w10 = W1[c], w11 = W1[64 + c], w12 = W1[128 + c];
    float b1c = b1[c], b2c = b2[c];

    int nidx[KNN];
#pragma unroll
    for (int k = 0; k < KNN; ++k)
        nidx[k] = idx[(size_t)k * BM + gq];      // wave-broadcast load

    float h[KNN];
#pragma unroll
    for (int k = 0; k < KNN; ++k) {
        const float* p = xyz1 + ((size_t)b * N + nidx[k]) * 3;
        float gx = p[0] - qx, gy = p[1] - qy, gz = p[2] - qz;
        float t = fmaf(gx, w10, b1c);
        t = fmaf(gy, w11, t);
        t = fmaf(gz, w12, t);
        h[k] = fmaxf(t, 0.f);
    }

#pragma unroll
    for (int k = 0; k < KNN; k += 4)
        *(float4*)&hT[wv][c * 16 + k] = make_float4(h[k], h[k+1], h[k+2], h[k+3]);

    __syncthreads();   // covers W2 staging + hT visibility

    float y[KNN];
#pragma unroll
    for (int k = 0; k < KNN; ++k) y[k] = 0.f;

#pragma unroll 4
    for (int d = 0; d < 64; ++d) {
        float w2dc = w2s[d * 64 + c];                       // conflict-free
        const float4* hp = (const float4*)&hT[wv][d * 16];  // broadcast reads
        float hh[16];
        *(float4*)&hh[0]  = hp[0];
        *(float4*)&hh[4]  = hp[1];
        *(float4*)&hh[8]  = hp[2];
        *(float4*)&hh[12] = hp[3];
#pragma unroll
        for (int k = 0; k < KNN; ++k)
            y[k] = fmaf(hh[k], w2dc, y[k]);
    }

    float acc = 0.f;
#pragma unroll
    for (int k = 0; k < KNN; ++k) {
        float gfv = f[((size_t)b * N + nidx[k]) * 64 + c];  // coalesced row
        acc = fmaf(y[k] + b2c, gfv, acc);
    }
    out[(size_t)gq * 64 + c] = acc * 0.25f;   // 1/sqrt(16)
}

extern "C" void kernel_launch(void* const* d_in, const int* in_sizes, int n_in,
                              void* d_out, int out_size, void* d_ws, size_t ws_size,
                              hipStream_t stream) {
    const float* feature1 = (const float*)d_in[0];
    const float* xyz1     = (const float*)d_in[1];
    const float* xyz2     = (const float*)d_in[2];
    const float* Wp       = (const float*)d_in[3];
    const float* bp       = (const float*)d_in[4];
    const float* W1       = (const float*)d_in[5];
    const float* b1       = (const float*)d_in[6];
    const float* W2       = (const float*)d_in[7];
    const float* b2       = (const float*)d_in[8];
    float* out = (float*)d_out;

    float4* pts4  = (float4*)d_ws;
    float*  f     = (float*)(pts4 + (size_t)B * N);
    float*  partd = f + (size_t)B * N * D;
    int*    parti = (int*)(partd + (size_t)NSLICE * KNN * BM);
    int*    idxf  = parti + (size_t)NSLICE * KNN * BM;
    float*  w_out = out + (size_t)BM * D;

    k_prep<<<B * N / 256, 256, 0, stream>>>(xyz1, pts4);
    k_proj<<<B * N / 4, 256, 0, stream>>>(feature1, Wp, bp, f);
    k_knn_part<<<(M / 256) * B * NSLICE, 256, 0, stream>>>(pts4, xyz2, partd, parti);
    k_knn_merge<<<BM / 64, 256, 0, stream>>>(xyz2, partd, parti, idxf, w_out);
    k_final<<<BM / 4, 256, 0, stream>>>(xyz1, xyz2, f, idxf, W1, b1, W2, b2, out);
}